// Round 1
// baseline (256.226 us; speedup 1.0000x reference)
//
#include <hip/hip_runtime.h>
#include <hip/hip_bf16.h>
#include <stdint.h>
#include <stddef.h>

typedef __bf16 bf16;
typedef bf16 bf16x8 __attribute__((ext_vector_type(8)));
typedef float f32x4 __attribute__((ext_vector_type(4)));

#define EPSN 1e-8f
#define TWO_PI 6.283185307179586f

#define NB 16384   // batch
#define NH 512     // hidden
#define NI 256     // input

__device__ __forceinline__ float2 cmul(float2 a, float2 b) {
  return make_float2(a.x * b.x - a.y * b.y, a.x * b.y + a.y * b.x);
}
// a * conj(b)
__device__ __forceinline__ float2 cmulconj(float2 a, float2 b) {
  return make_float2(a.x * b.x + a.y * b.y, a.y * b.x - a.x * b.y);
}
__device__ __forceinline__ float2 cadd(float2 a, float2 b) {
  return make_float2(a.x + b.x, a.y + b.y);
}
__device__ __forceinline__ int brev9(int i) {
  return (int)(__brev((unsigned)i) >> 23);
}

// ---------------------------------------------------------------------------
// Setup: d1,d2,d3 = exp(i*angles); v1,v2 = r/(||r||+eps). One block, 512 thr.
// ---------------------------------------------------------------------------
__global__ __launch_bounds__(512) void setup_kernel(
    const float* __restrict__ ang, const float* __restrict__ rre,
    const float* __restrict__ rim, float2* __restrict__ d1,
    float2* __restrict__ d2, float2* __restrict__ d3, float2* __restrict__ v1,
    float2* __restrict__ v2) {
  __shared__ float red[512];
  const int t = threadIdx.x;
  float s, c;
  __sincosf(ang[t], &s, &c);
  d1[t] = make_float2(c, s);
  __sincosf(ang[512 + t], &s, &c);
  d2[t] = make_float2(c, s);
  __sincosf(ang[1024 + t], &s, &c);
  d3[t] = make_float2(c, s);

  const float r1x = rre[t], r1y = rim[t];
  const float r2x = rre[512 + t], r2y = rim[512 + t];

  red[t] = r1x * r1x + r1y * r1y;
  __syncthreads();
  for (int off = 256; off > 0; off >>= 1) {
    if (t < off) red[t] += red[t + off];
    __syncthreads();
  }
  const float inv1 = 1.0f / (sqrtf(red[0]) + EPSN);
  __syncthreads();
  red[t] = r2x * r2x + r2y * r2y;
  __syncthreads();
  for (int off = 256; off > 0; off >>= 1) {
    if (t < off) red[t] += red[t + off];
    __syncthreads();
  }
  const float inv2 = 1.0f / (sqrtf(red[0]) + EPSN);
  v1[t] = make_float2(r1x * inv1, r1y * inv1);
  v2[t] = make_float2(r2x * inv2, r2y * inv2);
}

// ---------------------------------------------------------------------------
// GEMM: emb_re = x @ W_re^T, emb_im = x @ W_im^T.  M=16384, N=1024 (stacked),
// K=256. bf16 MFMA 16x16x32, 128x128 block tile, 4 waves (2x2), 4x4 acc each.
// fp32->bf16 conversion fused into LDS staging. LDS rows padded to 40 bf16
// (80 B) -> 2-way max bank aliasing on ds_read_b128/ds_write_b128 (free).
// ---------------------------------------------------------------------------
__global__ __launch_bounds__(256) void gemm_emb(
    const float* __restrict__ x, const float* __restrict__ wre,
    const float* __restrict__ wim, float* __restrict__ emb_re,
    float* __restrict__ emb_im) {
  __shared__ bf16 As[128 * 40];
  __shared__ bf16 Bs[128 * 40];

  const int t = threadIdx.x;
  const int lane = t & 63;
  const int wave = t >> 6;
  const int waveM = wave & 1;
  const int waveN = wave >> 1;
  const int mBase = blockIdx.x * 128;
  const int nBase = blockIdx.y * 128;  // 512 boundary is a multiple of 128
  const float* __restrict__ Wsrc = (nBase < 512) ? wre : wim;
  const int nOfs = (nBase < 512) ? nBase : (nBase - 512);

  f32x4 acc[4][4] = {};

  const int sr = t >> 2;         // staging row 0..63 (+64 for second half)
  const int sc = (t & 3) * 8;    // staging col in bf16 elems: 0,8,16,24
  const int lr = lane & 15;
  const int lq = lane >> 4;

  for (int kk = 0; kk < NI; kk += 32) {
#pragma unroll
    for (int h = 0; h < 2; ++h) {
      const int row = sr + h * 64;
      const float* gp = x + (size_t)(mBase + row) * NI + kk + sc;
      float4 f0 = ((const float4*)gp)[0];
      float4 f1 = ((const float4*)gp)[1];
      bf16x8 va;
      va[0] = (bf16)f0.x; va[1] = (bf16)f0.y; va[2] = (bf16)f0.z; va[3] = (bf16)f0.w;
      va[4] = (bf16)f1.x; va[5] = (bf16)f1.y; va[6] = (bf16)f1.z; va[7] = (bf16)f1.w;
      *(bf16x8*)(&As[row * 40 + sc]) = va;

      const float* gq = Wsrc + (size_t)(nOfs + row) * NI + kk + sc;
      float4 g0 = ((const float4*)gq)[0];
      float4 g1 = ((const float4*)gq)[1];
      bf16x8 vb;
      vb[0] = (bf16)g0.x; vb[1] = (bf16)g0.y; vb[2] = (bf16)g0.z; vb[3] = (bf16)g0.w;
      vb[4] = (bf16)g1.x; vb[5] = (bf16)g1.y; vb[6] = (bf16)g1.z; vb[7] = (bf16)g1.w;
      *(bf16x8*)(&Bs[row * 40 + sc]) = vb;
    }
    __syncthreads();

    bf16x8 af[4], bfr[4];
#pragma unroll
    for (int mi = 0; mi < 4; ++mi)
      af[mi] = *(const bf16x8*)(&As[(waveM * 64 + mi * 16 + lr) * 40 + lq * 8]);
#pragma unroll
    for (int ni = 0; ni < 4; ++ni)
      bfr[ni] = *(const bf16x8*)(&Bs[(waveN * 64 + ni * 16 + lr) * 40 + lq * 8]);
#pragma unroll
    for (int mi = 0; mi < 4; ++mi)
#pragma unroll
      for (int ni = 0; ni < 4; ++ni)
        acc[mi][ni] = __builtin_amdgcn_mfma_f32_16x16x32_bf16(
            af[mi], bfr[ni], acc[mi][ni], 0, 0, 0);
    __syncthreads();
  }

  // Epilogue. C/D layout: col = lane&15, row = (lane>>4)*4 + reg  (m89/m91).
  const int col = lane & 15;
  const int row0 = (lane >> 4) * 4;
#pragma unroll
  for (int ni = 0; ni < 4; ++ni) {
    const int n = nBase + waveN * 64 + ni * 16 + col;
    float* dst = (n < 512) ? emb_re : emb_im;
    const int nn = (n < 512) ? n : n - 512;
#pragma unroll
    for (int mi = 0; mi < 4; ++mi) {
      const int mrow = mBase + waveM * 64 + mi * 16 + row0;
#pragma unroll
      for (int r = 0; r < 4; ++r)
        dst[(size_t)(mrow + r) * NH + nn] = acc[mi][ni][r];
    }
  }
}

// ---------------------------------------------------------------------------
// Per-row pipeline: h = hx; FFT(d1*h); Householder(v1); IFFT(d2*h[perm]);
// d3*Householder(v2); + emb; ModReLU. One block (256 thr) per row, radix-2
// LDS FFT (9 stages fwd + 9 inv), block-wide complex dot for Householders.
// ---------------------------------------------------------------------------
__global__ __launch_bounds__(256) void urnn_row(
    const float* __restrict__ hxre, const float* __restrict__ hxim,
    const float2* __restrict__ d1, const float2* __restrict__ d2,
    const float2* __restrict__ d3, const float2* __restrict__ v1,
    const float2* __restrict__ v2, const int* __restrict__ perm,
    const float* __restrict__ beta, const float* __restrict__ emb_re,
    const float* __restrict__ emb_im, float2* __restrict__ out) {
  __shared__ float2 bufA[512];
  __shared__ float2 bufB[512];
  __shared__ float2 redw[4];
  __shared__ float2 bc;

  const int t = threadIdx.x;
  const int b = blockIdx.x;
  const int j0 = t, j1 = t + 256;
  const size_t rowOff = (size_t)b * NH;

  // load + x d1 + bit-reversed scatter into bufA
  {
    float2 h0 = make_float2(hxre[rowOff + j0], hxim[rowOff + j0]);
    float2 h1 = make_float2(hxre[rowOff + j1], hxim[rowOff + j1]);
    bufA[brev9(j0)] = cmul(d1[j0], h0);
    bufA[brev9(j1)] = cmul(d1[j1], h1);
  }
  __syncthreads();

  // forward FFT (e^{-2pi i})
#pragma unroll
  for (int st = 0; st < 9; ++st) {
    const int half = 1 << st;
    const int pos = t & (half - 1);
    const int i0 = ((t >> st) << (st + 1)) + pos;
    const int i1 = i0 + half;
    const float angv = -TWO_PI * (float)pos / (float)(2 << st);
    float sn, cs;
    __sincosf(angv, &sn, &cs);
    float2 u = bufA[i0];
    float2 w = bufA[i1];
    float2 tw = make_float2(cs * w.x - sn * w.y, cs * w.y + sn * w.x);
    bufA[i0] = make_float2(u.x + tw.x, u.y + tw.y);
    bufA[i1] = make_float2(u.x - tw.x, u.y - tw.y);
    __syncthreads();
  }

  // dot1 = sum_j h_j * v1_j  (no conj, per reference h @ v)
  const float2 v1a = v1[j0], v1b = v1[j1];
  {
    float2 p = cadd(cmul(bufA[j0], v1a), cmul(bufA[j1], v1b));
    for (int off = 32; off > 0; off >>= 1) {
      p.x += __shfl_down(p.x, off);
      p.y += __shfl_down(p.y, off);
    }
    if ((t & 63) == 0) redw[t >> 6] = p;
    __syncthreads();
    if (t == 0) bc = cadd(cadd(redw[0], redw[1]), cadd(redw[2], redw[3]));
    __syncthreads();
  }
  const float2 dot1 = bc;

  // Householder 1 in place: h_j -= 2*dot1*conj(v1_j)
  {
    float2 c0 = cmulconj(dot1, v1a);
    float2 c1 = cmulconj(dot1, v1b);
    float2 a0 = bufA[j0], a1 = bufA[j1];
    bufA[j0] = make_float2(a0.x - 2.f * c0.x, a0.y - 2.f * c0.y);
    bufA[j1] = make_float2(a1.x - 2.f * c1.x, a1.y - 2.f * c1.y);
  }
  __syncthreads();

  // permute + x d2 + bit-reversed scatter into bufB
  {
    int p0 = perm[j0], p1 = perm[j1];
    float2 g0 = cmul(d2[j0], bufA[p0]);
    float2 g1 = cmul(d2[j1], bufA[p1]);
    bufB[brev9(j0)] = g0;
    bufB[brev9(j1)] = g1;
  }
  __syncthreads();

  // inverse FFT (e^{+2pi i}, unscaled; 1/512 folded in below)
#pragma unroll
  for (int st = 0; st < 9; ++st) {
    const int half = 1 << st;
    const int pos = t & (half - 1);
    const int i0 = ((t >> st) << (st + 1)) + pos;
    const int i1 = i0 + half;
    const float angv = TWO_PI * (float)pos / (float)(2 << st);
    float sn, cs;
    __sincosf(angv, &sn, &cs);
    float2 u = bufB[i0];
    float2 w = bufB[i1];
    float2 tw = make_float2(cs * w.x - sn * w.y, cs * w.y + sn * w.x);
    bufB[i0] = make_float2(u.x + tw.x, u.y + tw.y);
    bufB[i1] = make_float2(u.x - tw.x, u.y - tw.y);
    __syncthreads();
  }

  // dot2 on unscaled ifft output
  const float2 v2a = v2[j0], v2b = v2[j1];
  {
    float2 q = cadd(cmul(bufB[j0], v2a), cmul(bufB[j1], v2b));
    for (int off = 32; off > 0; off >>= 1) {
      q.x += __shfl_down(q.x, off);
      q.y += __shfl_down(q.y, off);
    }
    if ((t & 63) == 0) redw[t >> 6] = q;
    __syncthreads();
    if (t == 0) bc = cadd(cadd(redw[0], redw[1]), cadd(redw[2], redw[3]));
    __syncthreads();
  }
  const float invN = 1.0f / 512.0f;
  const float2 dot2 = make_float2(bc.x * invN, bc.y * invN);

  // final elementwise: Householder2, d3, +emb, ModReLU, store
#pragma unroll
  for (int e = 0; e < 2; ++e) {
    const int j = (e == 0) ? j0 : j1;
    const float2 vj = (e == 0) ? v2a : v2b;
    float2 h2 = make_float2(bufB[j].x * invN, bufB[j].y * invN);
    float2 c2 = cmulconj(dot2, vj);
    float2 hh = make_float2(h2.x - 2.f * c2.x, h2.y - 2.f * c2.y);
    float2 h3 = cmul(d3[j], hh);
    float2 cc = make_float2(h3.x + emb_re[rowOff + j], h3.y + emb_im[rowOff + j]);
    float mag = sqrtf(cc.x * cc.x + cc.y * cc.y);
    float sc = mag + beta[j];
    float2 o;
    if (sc <= 0.f) {
      o = make_float2(0.f, 0.f);
    } else if (mag > 0.f) {
      float k = sc / mag;
      o = make_float2(cc.x * k, cc.y * k);
    } else {
      o = make_float2(sc, 0.f);  // mag==0: exp(i*angle(0)) == 1
    }
    out[rowOff + j] = o;
  }
}

// ---------------------------------------------------------------------------
extern "C" void kernel_launch(void* const* d_in, const int* in_sizes, int n_in,
                              void* d_out, int out_size, void* d_ws,
                              size_t ws_size, hipStream_t stream) {
  const float* x = (const float*)d_in[0];
  const float* hxre = (const float*)d_in[1];
  const float* hxim = (const float*)d_in[2];
  const float* ang = (const float*)d_in[3];
  const float* rre = (const float*)d_in[4];
  const float* rim = (const float*)d_in[5];
  const float* wre = (const float*)d_in[6];
  const float* wim = (const float*)d_in[7];
  const float* beta = (const float*)d_in[8];
  const int* perm = (const int*)d_in[9];

  char* ws = (char*)d_ws;
  float2* c_d1 = (float2*)ws;            // 512 float2
  float2* c_d2 = c_d1 + 512;
  float2* c_d3 = c_d2 + 512;
  float2* c_v1 = c_d3 + 512;
  float2* c_v2 = c_v1 + 512;
  float* emb_re = (float*)(ws + 32768);                  // 16384*512 f32
  float* emb_im = emb_re + (size_t)NB * NH;              // 16384*512 f32
  // total ws use: 32 KiB + 64 MiB

  setup_kernel<<<1, 512, 0, stream>>>(ang, rre, rim, c_d1, c_d2, c_d3, c_v1,
                                      c_v2);
  gemm_emb<<<dim3(NB / 128, 1024 / 128), 256, 0, stream>>>(x, wre, wim, emb_re,
                                                           emb_im);
  urnn_row<<<NB, 256, 0, stream>>>(hxre, hxim, c_d1, c_d2, c_d3, c_v1, c_v2,
                                   perm, beta, emb_re, emb_im, (float2*)d_out);
}